// Round 9
// baseline (648.813 us; speedup 1.0000x reference)
//
#include <hip/hip_runtime.h>
#include <hip/hip_fp16.h>

static constexpr int TPB       = 256;
static constexpr int MAXB      = 128;           // max bins (N <= 256K at 2048/bin)
static constexpr int BIN_SHIFT = 11;            // 2048 nodes per bin == accum tile
static constexpr int BINSZ     = 1 << BIN_SHIFT;
static constexpr int CAP       = 48;            // LDS bucket depth per bin
static constexpr int NBLKS     = 2048;          // scatter blocks
static constexpr int NBLKC     = 1024;          // count blocks
static constexpr int SSL       = 16;            // record slices per bin (B phase)
static constexpr int MAXG      = 64;
static constexpr int SLOTS     = MAXG * 6;      // 384 stress accumulators
static constexpr int NWAVES    = TPB / 64;

// -------------------------------------- A1: count + virial (streaming pass)
__global__ __launch_bounds__(TPB) void count_kernel(
    const float* __restrict__ rij, const float* __restrict__ fij,
    const int* __restrict__ idx0, const int* __restrict__ idx1,
    const int* __restrict__ batch,
    unsigned* __restrict__ g_hist, float* __restrict__ apart,
    int E, int nbins) {
    __shared__ unsigned hist[MAXB];
    __shared__ float s_acc[SLOTS];
    for (int t = threadIdx.x; t < nbins; t += TPB) hist[t] = 0u;
    for (int t = threadIdx.x; t < SLOTS; t += TPB) s_acc[t] = 0.0f;
    __syncthreads();

    const int NG = E >> 2;
    const int GC = (NG + NBLKC - 1) / NBLKC;
    const int g0 = blockIdx.x * GC;
    int g1 = g0 + GC; if (g1 > NG) g1 = NG;
    const int4* i04 = (const int4*)idx0;
    const int4* i14 = (const int4*)idx1;
    const float4* rij4 = (const float4*)rij;
    const float4* fij4 = (const float4*)fij;

    for (int k = g0 + threadIdx.x; k < g1; k += TPB) {
        int4 a = i04[k], b = i14[k];
        atomicAdd(&hist[((unsigned)a.x) >> BIN_SHIFT], 1u);
        atomicAdd(&hist[((unsigned)a.y) >> BIN_SHIFT], 1u);
        atomicAdd(&hist[((unsigned)a.z) >> BIN_SHIFT], 1u);
        atomicAdd(&hist[((unsigned)a.w) >> BIN_SHIFT], 1u);
        atomicAdd(&hist[((unsigned)b.x) >> BIN_SHIFT], 1u);
        atomicAdd(&hist[((unsigned)b.y) >> BIN_SHIFT], 1u);
        atomicAdd(&hist[((unsigned)b.z) >> BIN_SHIFT], 1u);
        atomicAdd(&hist[((unsigned)b.w) >> BIN_SHIFT], 1u);

        float4 fa = fij4[3 * k], fb = fij4[3 * k + 1], fc = fij4[3 * k + 2];
        float4 ra = rij4[3 * k], rb = rij4[3 * k + 1], rc = rij4[3 * k + 2];
        float fx[4] = {fa.x, fa.w, fb.z, fc.y};
        float fy[4] = {fa.y, fb.x, fb.w, fc.z};
        float fz[4] = {fa.z, fb.y, fc.x, fc.w};
        float rx[4] = {ra.x, ra.w, rb.z, rc.y};
        float ry[4] = {ra.y, rb.x, rb.w, rc.z};
        float rz[4] = {ra.z, rb.y, rc.x, rc.w};
        int r[4] = {b.x, b.y, b.z, b.w};
#pragma unroll
        for (int e = 0; e < 4; ++e) {
            int g = batch[r[e]];
            float* s = &s_acc[6 * g];
            atomicAdd(&s[0], rx[e] * fx[e]);
            atomicAdd(&s[1], ry[e] * fy[e]);
            atomicAdd(&s[2], rz[e] * fz[e]);
            atomicAdd(&s[3], rx[e] * fy[e]);
            atomicAdd(&s[4], ry[e] * fz[e]);
            atomicAdd(&s[5], rz[e] * fx[e]);
        }
    }
    if (blockIdx.x == 0) {  // scalar tail (E % 4)
        for (int e = (NG << 2) + threadIdx.x; e < E; e += TPB) {
            atomicAdd(&hist[((unsigned)idx0[e]) >> BIN_SHIFT], 1u);
            atomicAdd(&hist[((unsigned)idx1[e]) >> BIN_SHIFT], 1u);
            float ex = rij[3 * e], ey = rij[3 * e + 1], ez = rij[3 * e + 2];
            float gx = fij[3 * e], gy = fij[3 * e + 1], gz = fij[3 * e + 2];
            int g = batch[idx1[e]];
            float* s = &s_acc[6 * g];
            atomicAdd(&s[0], ex * gx);
            atomicAdd(&s[1], ey * gy);
            atomicAdd(&s[2], ez * gz);
            atomicAdd(&s[3], ex * gy);
            atomicAdd(&s[4], ey * gz);
            atomicAdd(&s[5], ez * gx);
        }
    }
    __syncthreads();
    for (int t = threadIdx.x; t < nbins; t += TPB)
        g_hist[(size_t)t * NBLKC + blockIdx.x] = hist[t];
    for (int t = threadIdx.x; t < SLOTS; t += TPB)
        apart[(size_t)t * NBLKC + blockIdx.x] = s_acc[t];
}

// ------------------------------------------- SCAN: bin totals/bases (1 block)
__global__ __launch_bounds__(TPB) void scan_kernel(
    const unsigned* __restrict__ g_hist,
    unsigned* __restrict__ bin_base, unsigned* __restrict__ bin_count,
    unsigned* __restrict__ cursor, int nbins) {
    __shared__ unsigned part[TPB];
    __shared__ unsigned tot[MAXB], base[MAXB];
    int b = threadIdx.x >> 1, q = threadIdx.x & 1;
    unsigned s = 0;
    if (b < nbins)
        for (int j = q; j < NBLKC; j += 2) s += g_hist[(size_t)b * NBLKC + j];
    part[threadIdx.x] = s;
    __syncthreads();
    if (threadIdx.x < (unsigned)nbins)
        tot[threadIdx.x] = part[threadIdx.x * 2] + part[threadIdx.x * 2 + 1];
    __syncthreads();
    if (threadIdx.x == 0) {
        unsigned run = 0;
        for (int i = 0; i < nbins; ++i) { base[i] = run; run += tot[i]; }
    }
    __syncthreads();
    if (threadIdx.x < (unsigned)nbins) {
        bin_base[threadIdx.x] = base[threadIdx.x];
        bin_count[threadIdx.x] = tot[threadIdx.x];
        cursor[threadIdx.x] = base[threadIdx.x];
    }
}

// ------------------------------------------------------------- A3: scatter
__device__ inline uint2 pack_rec(int node, float fx, float fy, float fz) {
    unsigned lid = (unsigned)node & (BINSZ - 1);
    unsigned w0 = (unsigned)__half_as_ushort(__float2half(fx)) |
                  ((unsigned)__half_as_ushort(__float2half(fy)) << 16);
    unsigned w1 = (unsigned)__half_as_ushort(__float2half(fz)) | (lid << 16);
    return make_uint2(w0, w1);
}

__device__ inline void emit(uint2* __restrict__ rec, unsigned* __restrict__ cursor,
                            unsigned* __restrict__ cnt, uint2* __restrict__ buf,
                            int node, float fx, float fy, float fz) {
    int b = node >> BIN_SHIFT;
    uint2 w = pack_rec(node, fx, fy, fz);
    unsigned slot = atomicAdd(&cnt[b], 1u);
    if (slot < (unsigned)CAP) buf[b * CAP + slot] = w;
    else { unsigned d = atomicAdd(&cursor[b], 1u); rec[d] = w; }  // rare overflow
}

__global__ __launch_bounds__(TPB) void scatter_kernel(
    const float* __restrict__ fij,
    const int* __restrict__ idx0, const int* __restrict__ idx1,
    unsigned* __restrict__ cursor, uint2* __restrict__ rec,
    int E, int nbins) {
    extern __shared__ char smem[];
    uint2* buf = (uint2*)smem;                                   // nbins*CAP
    unsigned* cnt = (unsigned*)(buf + (size_t)nbins * CAP);      // nbins
    unsigned* base_s = cnt + nbins;                              // nbins

    for (int t = threadIdx.x; t < nbins; t += TPB) cnt[t] = 0u;
    __syncthreads();

    const int NG = E >> 2;
    const int GC = (NG + NBLKS - 1) / NBLKS;
    const int g0 = blockIdx.x * GC;
    int g1 = g0 + GC; if (g1 > NG) g1 = NG;
    const int span = g1 - g0;
    const int niter = span > 0 ? (span + TPB - 1) / TPB : 0;

    const float4* fij4 = (const float4*)fij;
    const int4* i04 = (const int4*)idx0;
    const int4* i14 = (const int4*)idx1;

    const int wid = threadIdx.x >> 6, lane = threadIdx.x & 63;

    for (int it = 0; it < niter; ++it) {
        int k = g0 + it * TPB + threadIdx.x;
        if (k < g1) {
            float4 fa = fij4[3 * k], fb = fij4[3 * k + 1], fc = fij4[3 * k + 2];
            int4 i0 = i04[k], i1 = i14[k];
            float fx[4] = {fa.x, fa.w, fb.z, fc.y};
            float fy[4] = {fa.y, fb.x, fb.w, fc.z};
            float fz[4] = {fa.z, fb.y, fc.x, fc.w};
            int s[4] = {i0.x, i0.y, i0.z, i0.w};
            int r[4] = {i1.x, i1.y, i1.z, i1.w};
#pragma unroll
            for (int e = 0; e < 4; ++e) {
                emit(rec, cursor, cnt, buf, s[e], fx[e], fy[e], fz[e]);
                emit(rec, cursor, cnt, buf, r[e], -fx[e], -fy[e], -fz[e]);
            }
        }
        __syncthreads();
        // F1: bulk slot reservation — one parallel vector atomic (lanes = bins)
        if (threadIdx.x < (unsigned)nbins) {
            unsigned c = cnt[threadIdx.x];
            unsigned m = c < (unsigned)CAP ? c : (unsigned)CAP;
            base_s[threadIdx.x] = m ? atomicAdd(&cursor[threadIdx.x], m) : 0u;
        }
        __syncthreads();
        // F2: coalesced wave flush + fold counter zeroing into the same pass
        for (int b = wid; b < nbins; b += NWAVES) {
            unsigned c = cnt[b];
            unsigned m = c < (unsigned)CAP ? c : (unsigned)CAP;
            if ((unsigned)lane < m) rec[base_s[b] + lane] = buf[b * CAP + lane];
            if (lane == 0) cnt[b] = 0u;
        }
        __syncthreads();
    }

    // scalar tail (E % 4): block 0, direct reservation
    if (blockIdx.x == 0) {
        for (int e = (NG << 2) + threadIdx.x; e < E; e += TPB) {
            float gx = fij[3 * e], gy = fij[3 * e + 1], gz = fij[3 * e + 2];
            int si = idx0[e], ri = idx1[e];
            unsigned d0 = atomicAdd(&cursor[si >> BIN_SHIFT], 1u);
            rec[d0] = pack_rec(si, gx, gy, gz);
            unsigned d1 = atomicAdd(&cursor[ri >> BIN_SHIFT], 1u);
            rec[d1] = pack_rec(ri, -gx, -gy, -gz);
        }
    }
}

// ------------------------------------------------------------- B: accumulate
__global__ __launch_bounds__(TPB) void bin_accum_kernel(
    const uint2* __restrict__ rec,
    const unsigned* __restrict__ bin_base, const unsigned* __restrict__ bin_count,
    float* __restrict__ bpart) {
    __shared__ float lf[BINSZ * 3];                    // 24KB
    const int sl = blockIdx.x % SSL;
    const int bin = blockIdx.x / SSL;

    float4* lf4 = (float4*)lf;
    for (int t = threadIdx.x; t < BINSZ * 3 / 4; t += TPB)
        lf4[t] = make_float4(0.f, 0.f, 0.f, 0.f);
    __syncthreads();

    const unsigned base = bin_base[bin], cntb = bin_count[bin];
    const unsigned chunk = (cntb + SSL - 1) / SSL;
    unsigned r0 = (unsigned)sl * chunk;
    unsigned r1 = r0 + chunk;
    if (r0 > cntb) r0 = cntb;
    if (r1 > cntb) r1 = cntb;
#pragma unroll 4
    for (unsigned r = r0 + threadIdx.x; r < r1; r += TPB) {
        uint2 w = rec[(size_t)base + r];
        unsigned lid = w.y >> 16;
        float fx = __half2float(__ushort_as_half((unsigned short)(w.x & 0xffffu)));
        float fy = __half2float(__ushort_as_half((unsigned short)(w.x >> 16)));
        float fz = __half2float(__ushort_as_half((unsigned short)(w.y & 0xffffu)));
        atomicAdd(&lf[lid * 3 + 0], fx);
        atomicAdd(&lf[lid * 3 + 1], fy);
        atomicAdd(&lf[lid * 3 + 2], fz);
    }
    __syncthreads();
    float4* dst = (float4*)(bpart + (size_t)blockIdx.x * (BINSZ * 3));
    for (int t = threadIdx.x; t < BINSZ * 3 / 4; t += TPB) dst[t] = lf4[t];
}

// ------------------------------------------------------------- C: force out
__global__ __launch_bounds__(TPB) void force_kernel(
    const float* __restrict__ bpart, const float* __restrict__ pos_grad,
    float* __restrict__ force, long n3) {
    long j = (long)blockIdx.x * TPB + threadIdx.x;
    const long gs = (long)gridDim.x * TPB;
    for (; j < n3; j += gs) {
        unsigned i = (unsigned)(j / 3);
        unsigned c = (unsigned)(j - 3L * i);
        unsigned bin = i >> BIN_SHIFT;
        unsigned lid = i & (BINSZ - 1);
        float acc = -pos_grad[j];
        size_t tb = (size_t)bin * SSL * (BINSZ * 3) + lid * 3 + c;
#pragma unroll
        for (int sl = 0; sl < SSL; ++sl)
            acc += bpart[tb + (size_t)sl * (BINSZ * 3)];
        force[j] = acc;
    }
}

// ------------------------------------------------------------- R: stress out
__global__ __launch_bounds__(TPB) void stress_kernel(
    const float* __restrict__ apart,
    const float* __restrict__ cell_grad, const float* __restrict__ les_cell,
    const float* __restrict__ vol, float* __restrict__ stress, int slots) {
    int t = blockIdx.x;
    if (t >= slots) return;
    __shared__ float red[TPB];
    float s = 0.f;
    const float* row = apart + (size_t)t * NBLKC;
    for (int j = threadIdx.x; j < NBLKC; j += TPB) s += row[j];
    red[threadIdx.x] = s;
    __syncthreads();
    for (int w = TPB / 2; w > 0; w >>= 1) {
        if (threadIdx.x < w) red[threadIdx.x] += red[threadIdx.x + w];
        __syncthreads();
    }
    if (threadIdx.x == 0) {
        int g = t / 6, c = t - 6 * g;
        const int va[6] = {0, 1, 2, 0, 1, 0};
        const int vb[6] = {0, 1, 2, 1, 2, 2};
        int a = va[c], bb = vb[c];
        const float* L = les_cell + 9 * g;
        const float* Gm = cell_grad + 9 * g;
        float lr = L[a] * Gm[bb] + L[3 + a] * Gm[3 + bb] + L[6 + a] * Gm[6 + bb];
        stress[t] = (-red[0] - lr) / vol[g];
    }
}

// ---------------------------------------------------- fallback (round-1 path)
__global__ void init_force_kernel(const float4* __restrict__ pg4,
                                  float4* __restrict__ f4, int n4,
                                  const float* __restrict__ pg,
                                  float* __restrict__ f, int n) {
    int i = blockIdx.x * blockDim.x + threadIdx.x;
    int s = gridDim.x * blockDim.x;
    for (int k = i; k < n4; k += s) {
        float4 v = pg4[k];
        f4[k] = make_float4(-v.x, -v.y, -v.z, -v.w);
    }
    for (int k = n4 * 4 + i; k < n; k += s) f[k] = -pg[k];
}

__global__ __launch_bounds__(256) void edge_dev_kernel(
    const float* __restrict__ rij, const float* __restrict__ fij,
    const int* __restrict__ idx0, const int* __restrict__ idx1,
    const int* __restrict__ batch,
    float* __restrict__ force, float* __restrict__ partials, int E) {
    __shared__ float s_acc[SLOTS];
    for (int t = threadIdx.x; t < SLOTS; t += blockDim.x) s_acc[t] = 0.0f;
    __syncthreads();
    const int stride = gridDim.x * blockDim.x;
    const int tid0 = blockIdx.x * blockDim.x + threadIdx.x;
    for (int e = tid0; e < E; e += stride) {
        float ex = rij[3 * e], ey = rij[3 * e + 1], ez = rij[3 * e + 2];
        float gx = fij[3 * e], gy = fij[3 * e + 1], gz = fij[3 * e + 2];
        int si = idx0[e], ri = idx1[e];
        atomicAdd(&force[3 * si + 0], gx);
        atomicAdd(&force[3 * si + 1], gy);
        atomicAdd(&force[3 * si + 2], gz);
        atomicAdd(&force[3 * ri + 0], -gx);
        atomicAdd(&force[3 * ri + 1], -gy);
        atomicAdd(&force[3 * ri + 2], -gz);
        int g = batch[ri];
        float* a = &s_acc[6 * g];
        atomicAdd(&a[0], ex * gx);
        atomicAdd(&a[1], ey * gy);
        atomicAdd(&a[2], ez * gz);
        atomicAdd(&a[3], ex * gy);
        atomicAdd(&a[4], ey * gz);
        atomicAdd(&a[5], ez * gx);
    }
    __syncthreads();
    for (int t = threadIdx.x; t < SLOTS; t += blockDim.x)
        partials[(size_t)blockIdx.x * SLOTS + t] = s_acc[t];
}

__global__ void reduce_finalize_kernel(const float* __restrict__ partials, int nblocks,
                                       const float* __restrict__ cell_grad,
                                       const float* __restrict__ les_cell,
                                       const float* __restrict__ vol,
                                       float* __restrict__ stress_out, int slots) {
    int t = blockIdx.x * blockDim.x + threadIdx.x;
    if (t >= slots) return;
    float s = 0.0f;
    for (int b = 0; b < nblocks; ++b) s += partials[(size_t)b * SLOTS + t];
    int g = t / 6, c = t - 6 * g;
    const int va[6] = {0, 1, 2, 0, 1, 0};
    const int vb[6] = {0, 1, 2, 1, 2, 2};
    int a = va[c], bb = vb[c];
    const float* L = les_cell + 9 * g;
    const float* G = cell_grad + 9 * g;
    float lr = L[a] * G[bb] + L[3 + a] * G[3 + bb] + L[6 + a] * G[6 + bb];
    stress_out[t] = (-s - lr) / vol[g];
}

// ------------------------------------------------------------------ launcher
static inline size_t alignup(size_t x) { return (x + 255) & ~(size_t)255; }

extern "C" void kernel_launch(void* const* d_in, const int* in_sizes, int n_in,
                              void* d_out, int out_size, void* d_ws, size_t ws_size,
                              hipStream_t stream) {
    const float* rij = (const float*)d_in[0];
    const float* fij = (const float*)d_in[1];
    const float* pos_grad = (const float*)d_in[2];
    const float* cell_grad = (const float*)d_in[3];
    const float* les_cell = (const float*)d_in[4];
    const float* vol = (const float*)d_in[5];
    const int* edge_idx = (const int*)d_in[6];
    const int* batch = (const int*)d_in[7];

    const int E = in_sizes[0] / 3;
    const int N = in_sizes[2] / 3;
    const int ngr = in_sizes[5];
    const int slots = 6 * ngr;

    float* force = (float*)d_out;
    float* stress = (float*)d_out + (size_t)N * 3;

    const int nbins = (N + BINSZ - 1) >> BIN_SHIFT;
    const long N3 = (long)N * 3;

    // workspace layout
    size_t off = 0;
    const size_t o_rec = off;   off += alignup((size_t)2 * E * 8);
    const size_t o_hist = off;  off += alignup((size_t)MAXB * NBLKC * 4);
    const size_t o_base = off;  off += alignup(MAXB * 4);
    const size_t o_cnt = off;   off += alignup(MAXB * 4);
    const size_t o_cur = off;   off += alignup(MAXB * 4);
    const size_t o_apart = off; off += alignup((size_t)SLOTS * NBLKC * 4);
    const size_t o_bpart = off; off += alignup((size_t)nbins * SSL * (BINSZ * 3) * 4);
    const bool fit = (off <= ws_size) && (nbins <= MAXB) && (ngr <= MAXG) && (E >= 4);

    if (fit) {
        char* ws = (char*)d_ws;
        uint2* rec = (uint2*)(ws + o_rec);
        unsigned* g_hist = (unsigned*)(ws + o_hist);
        unsigned* bin_base = (unsigned*)(ws + o_base);
        unsigned* bin_count = (unsigned*)(ws + o_cnt);
        unsigned* cursor = (unsigned*)(ws + o_cur);
        float* apart = (float*)(ws + o_apart);
        float* bpart = (float*)(ws + o_bpart);

        count_kernel<<<NBLKC, TPB, 0, stream>>>(
            rij, fij, edge_idx, edge_idx + E, batch, g_hist, apart, E, nbins);
        scan_kernel<<<1, TPB, 0, stream>>>(g_hist, bin_base, bin_count, cursor, nbins);

        const size_t smem = (size_t)nbins * CAP * 8 + (size_t)nbins * 8;
        scatter_kernel<<<NBLKS, TPB, smem, stream>>>(
            fij, edge_idx, edge_idx + E, cursor, rec, E, nbins);

        bin_accum_kernel<<<nbins * SSL, TPB, 0, stream>>>(
            rec, bin_base, bin_count, bpart);

        int fblocks = (int)((N3 + TPB - 1) / TPB);
        if (fblocks > 4096) fblocks = 4096;
        force_kernel<<<fblocks, TPB, 0, stream>>>(bpart, pos_grad, force, N3);

        stress_kernel<<<slots, TPB, 0, stream>>>(apart, cell_grad, les_cell, vol,
                                                 stress, slots);
    } else {
        // device-atomic fallback (proven correct, slow)
        float* partials = (float*)d_ws;
        int eblocks = 512;
        size_t need = (size_t)eblocks * SLOTS * sizeof(float);
        if (need > ws_size) {
            int fit2 = (int)(ws_size / (SLOTS * sizeof(float)));
            eblocks = fit2 > 0 ? fit2 : 1;
        }
        int n = (int)N3, n4 = n / 4;
        int blocks = (n4 + 255) / 256;
        if (blocks > 1024) blocks = 1024;
        if (blocks < 1) blocks = 1;
        init_force_kernel<<<blocks, 256, 0, stream>>>(
            (const float4*)pos_grad, (float4*)force, n4, pos_grad, force, n);
        edge_dev_kernel<<<eblocks, 256, 0, stream>>>(rij, fij, edge_idx, edge_idx + E,
                                                     batch, force, partials, E);
        reduce_finalize_kernel<<<6, 64, 0, stream>>>(partials, eblocks, cell_grad,
                                                     les_cell, vol, stress, slots);
    }
}

// Round 10
// 327.407 us; speedup vs baseline: 1.9817x; 1.9817x over previous
//
#include <hip/hip_runtime.h>
#include <hip/hip_fp16.h>

static constexpr int TPB       = 256;
static constexpr int MAXB      = 128;           // max bins (N <= 256K at 2048/bin)
static constexpr int BIN_SHIFT = 11;            // 2048 nodes per bin == accum tile
static constexpr int BINSZ     = 1 << BIN_SHIFT;
static constexpr int CAP       = 48;            // LDS bucket depth per bin
static constexpr int NBLKS     = 2048;          // scatter blocks
static constexpr int NBLKC     = 1024;          // count blocks
static constexpr int SSL       = 16;            // record slices per bin (B phase)
static constexpr int MAXG      = 64;
static constexpr int SLOTS     = MAXG * 6;      // 384 stress accumulators
static constexpr int NWAVES    = TPB / 64;

static constexpr float VSCALE  = 4096.0f;       // virial fixed-point (2^12)
static constexpr float VINV    = 1.0f / 4096.0f;
static constexpr float FSCALE  = 1048576.0f;    // force fixed-point (2^20)
static constexpr float FINV    = 1.0f / 1048576.0f;

// -------------------------------------- A1: count + virial (streaming pass)
__global__ __launch_bounds__(TPB) void count_kernel(
    const float* __restrict__ rij, const float* __restrict__ fij,
    const int* __restrict__ idx0, const int* __restrict__ idx1,
    const int* __restrict__ batch,
    unsigned* __restrict__ g_hist, float* __restrict__ apart,
    int E, int nbins) {
    __shared__ unsigned hist[MAXB];
    __shared__ int s_acc[SLOTS];
    for (int t = threadIdx.x; t < nbins; t += TPB) hist[t] = 0u;
    for (int t = threadIdx.x; t < SLOTS; t += TPB) s_acc[t] = 0;
    __syncthreads();

    const int NG = E >> 2;
    const int GC = (NG + NBLKC - 1) / NBLKC;
    const int g0 = blockIdx.x * GC;
    int g1 = g0 + GC; if (g1 > NG) g1 = NG;
    const int4* i04 = (const int4*)idx0;
    const int4* i14 = (const int4*)idx1;
    const float4* rij4 = (const float4*)rij;
    const float4* fij4 = (const float4*)fij;

    for (int k = g0 + threadIdx.x; k < g1; k += TPB) {
        int4 a = i04[k], b = i14[k];
        atomicAdd(&hist[((unsigned)a.x) >> BIN_SHIFT], 1u);
        atomicAdd(&hist[((unsigned)a.y) >> BIN_SHIFT], 1u);
        atomicAdd(&hist[((unsigned)a.z) >> BIN_SHIFT], 1u);
        atomicAdd(&hist[((unsigned)a.w) >> BIN_SHIFT], 1u);
        atomicAdd(&hist[((unsigned)b.x) >> BIN_SHIFT], 1u);
        atomicAdd(&hist[((unsigned)b.y) >> BIN_SHIFT], 1u);
        atomicAdd(&hist[((unsigned)b.z) >> BIN_SHIFT], 1u);
        atomicAdd(&hist[((unsigned)b.w) >> BIN_SHIFT], 1u);

        float4 fa = fij4[3 * k], fb = fij4[3 * k + 1], fc = fij4[3 * k + 2];
        float4 ra = rij4[3 * k], rb = rij4[3 * k + 1], rc = rij4[3 * k + 2];
        float fx[4] = {fa.x, fa.w, fb.z, fc.y};
        float fy[4] = {fa.y, fb.x, fb.w, fc.z};
        float fz[4] = {fa.z, fb.y, fc.x, fc.w};
        float rx[4] = {ra.x, ra.w, rb.z, rc.y};
        float ry[4] = {ra.y, rb.x, rb.w, rc.z};
        float rz[4] = {ra.z, rb.y, rc.x, rc.w};
        int r[4] = {b.x, b.y, b.z, b.w};
#pragma unroll
        for (int e = 0; e < 4; ++e) {
            int g = batch[r[e]];
            int* s = &s_acc[6 * g];
            atomicAdd(&s[0], __float2int_rn(rx[e] * fx[e] * VSCALE));
            atomicAdd(&s[1], __float2int_rn(ry[e] * fy[e] * VSCALE));
            atomicAdd(&s[2], __float2int_rn(rz[e] * fz[e] * VSCALE));
            atomicAdd(&s[3], __float2int_rn(rx[e] * fy[e] * VSCALE));
            atomicAdd(&s[4], __float2int_rn(ry[e] * fz[e] * VSCALE));
            atomicAdd(&s[5], __float2int_rn(rz[e] * fx[e] * VSCALE));
        }
    }
    if (blockIdx.x == 0) {  // scalar tail (E % 4)
        for (int e = (NG << 2) + threadIdx.x; e < E; e += TPB) {
            atomicAdd(&hist[((unsigned)idx0[e]) >> BIN_SHIFT], 1u);
            atomicAdd(&hist[((unsigned)idx1[e]) >> BIN_SHIFT], 1u);
            float ex = rij[3 * e], ey = rij[3 * e + 1], ez = rij[3 * e + 2];
            float gx = fij[3 * e], gy = fij[3 * e + 1], gz = fij[3 * e + 2];
            int g = batch[idx1[e]];
            int* s = &s_acc[6 * g];
            atomicAdd(&s[0], __float2int_rn(ex * gx * VSCALE));
            atomicAdd(&s[1], __float2int_rn(ey * gy * VSCALE));
            atomicAdd(&s[2], __float2int_rn(ez * gz * VSCALE));
            atomicAdd(&s[3], __float2int_rn(ex * gy * VSCALE));
            atomicAdd(&s[4], __float2int_rn(ey * gz * VSCALE));
            atomicAdd(&s[5], __float2int_rn(ez * gx * VSCALE));
        }
    }
    __syncthreads();
    for (int t = threadIdx.x; t < nbins; t += TPB)
        g_hist[(size_t)t * NBLKC + blockIdx.x] = hist[t];
    for (int t = threadIdx.x; t < SLOTS; t += TPB)
        apart[(size_t)t * NBLKC + blockIdx.x] = (float)s_acc[t] * VINV;
}

// ------------------------------------------- SCAN: bin totals/bases (1 block)
__global__ __launch_bounds__(TPB) void scan_kernel(
    const unsigned* __restrict__ g_hist,
    unsigned* __restrict__ bin_base, unsigned* __restrict__ bin_count,
    unsigned* __restrict__ cursor, int nbins) {
    __shared__ unsigned part[TPB];
    __shared__ unsigned tot[MAXB], base[MAXB];
    int b = threadIdx.x >> 1, q = threadIdx.x & 1;
    unsigned s = 0;
    if (b < nbins)
        for (int j = q; j < NBLKC; j += 2) s += g_hist[(size_t)b * NBLKC + j];
    part[threadIdx.x] = s;
    __syncthreads();
    if (threadIdx.x < (unsigned)nbins)
        tot[threadIdx.x] = part[threadIdx.x * 2] + part[threadIdx.x * 2 + 1];
    __syncthreads();
    if (threadIdx.x == 0) {
        unsigned run = 0;
        for (int i = 0; i < nbins; ++i) { base[i] = run; run += tot[i]; }
    }
    __syncthreads();
    if (threadIdx.x < (unsigned)nbins) {
        bin_base[threadIdx.x] = base[threadIdx.x];
        bin_count[threadIdx.x] = tot[threadIdx.x];
        cursor[threadIdx.x] = base[threadIdx.x];
    }
}

// ------------------------------------------------------------- A3: scatter
__device__ inline uint2 pack_rec(int node, float fx, float fy, float fz) {
    unsigned lid = (unsigned)node & (BINSZ - 1);
    unsigned w0 = (unsigned)__half_as_ushort(__float2half(fx)) |
                  ((unsigned)__half_as_ushort(__float2half(fy)) << 16);
    unsigned w1 = (unsigned)__half_as_ushort(__float2half(fz)) | (lid << 16);
    return make_uint2(w0, w1);
}

__device__ inline void emit(uint2* __restrict__ rec, unsigned* __restrict__ cursor,
                            unsigned* __restrict__ cnt, uint2* __restrict__ buf,
                            int node, float fx, float fy, float fz) {
    int b = node >> BIN_SHIFT;
    uint2 w = pack_rec(node, fx, fy, fz);
    unsigned slot = atomicAdd(&cnt[b], 1u);
    if (slot < (unsigned)CAP) buf[b * CAP + slot] = w;
    else { unsigned d = atomicAdd(&cursor[b], 1u); rec[d] = w; }  // rare overflow
}

__global__ __launch_bounds__(TPB) void scatter_kernel(
    const float* __restrict__ fij,
    const int* __restrict__ idx0, const int* __restrict__ idx1,
    unsigned* __restrict__ cursor, uint2* __restrict__ rec,
    int E, int nbins) {
    extern __shared__ char smem[];
    uint2* buf = (uint2*)smem;                                   // nbins*CAP
    unsigned* cnt = (unsigned*)(buf + (size_t)nbins * CAP);      // nbins
    unsigned* base_s = cnt + nbins;                              // nbins

    for (int t = threadIdx.x; t < nbins; t += TPB) cnt[t] = 0u;
    __syncthreads();

    const int NG = E >> 2;
    const int GC = (NG + NBLKS - 1) / NBLKS;
    const int g0 = blockIdx.x * GC;
    int g1 = g0 + GC; if (g1 > NG) g1 = NG;
    const int span = g1 - g0;
    const int niter = span > 0 ? (span + TPB - 1) / TPB : 0;

    const float4* fij4 = (const float4*)fij;
    const int4* i04 = (const int4*)idx0;
    const int4* i14 = (const int4*)idx1;

    const int wid = threadIdx.x >> 6, lane = threadIdx.x & 63;

    for (int it = 0; it < niter; ++it) {
        int k = g0 + it * TPB + threadIdx.x;
        if (k < g1) {
            float4 fa = fij4[3 * k], fb = fij4[3 * k + 1], fc = fij4[3 * k + 2];
            int4 i0 = i04[k], i1 = i14[k];
            float fx[4] = {fa.x, fa.w, fb.z, fc.y};
            float fy[4] = {fa.y, fb.x, fb.w, fc.z};
            float fz[4] = {fa.z, fb.y, fc.x, fc.w};
            int s[4] = {i0.x, i0.y, i0.z, i0.w};
            int r[4] = {i1.x, i1.y, i1.z, i1.w};
#pragma unroll
            for (int e = 0; e < 4; ++e) {
                emit(rec, cursor, cnt, buf, s[e], fx[e], fy[e], fz[e]);
                emit(rec, cursor, cnt, buf, r[e], -fx[e], -fy[e], -fz[e]);
            }
        }
        __syncthreads();
        // F1: bulk slot reservation — one parallel vector atomic (lanes = bins)
        if (threadIdx.x < (unsigned)nbins) {
            unsigned c = cnt[threadIdx.x];
            unsigned m = c < (unsigned)CAP ? c : (unsigned)CAP;
            base_s[threadIdx.x] = m ? atomicAdd(&cursor[threadIdx.x], m) : 0u;
        }
        __syncthreads();
        // F2: coalesced wave flush + fold counter zeroing into the same pass
        for (int b = wid; b < nbins; b += NWAVES) {
            unsigned c = cnt[b];
            unsigned m = c < (unsigned)CAP ? c : (unsigned)CAP;
            if ((unsigned)lane < m) rec[base_s[b] + lane] = buf[b * CAP + lane];
            if (lane == 0) cnt[b] = 0u;
        }
        __syncthreads();
    }

    // scalar tail (E % 4): block 0, direct reservation
    if (blockIdx.x == 0) {
        for (int e = (NG << 2) + threadIdx.x; e < E; e += TPB) {
            float gx = fij[3 * e], gy = fij[3 * e + 1], gz = fij[3 * e + 2];
            int si = idx0[e], ri = idx1[e];
            unsigned d0 = atomicAdd(&cursor[si >> BIN_SHIFT], 1u);
            rec[d0] = pack_rec(si, gx, gy, gz);
            unsigned d1 = atomicAdd(&cursor[ri >> BIN_SHIFT], 1u);
            rec[d1] = pack_rec(ri, -gx, -gy, -gz);
        }
    }
}

// ------------------------------------------------------------- B: accumulate
__global__ __launch_bounds__(TPB) void bin_accum_kernel(
    const uint2* __restrict__ rec,
    const unsigned* __restrict__ bin_base, const unsigned* __restrict__ bin_count,
    float* __restrict__ bpart) {
    __shared__ int lf[BINSZ * 3];                      // 24KB, fixed-point 2^20
    const int sl = blockIdx.x % SSL;
    const int bin = blockIdx.x / SSL;

    int4* lf4 = (int4*)lf;
    for (int t = threadIdx.x; t < BINSZ * 3 / 4; t += TPB)
        lf4[t] = make_int4(0, 0, 0, 0);
    __syncthreads();

    const unsigned base = bin_base[bin], cntb = bin_count[bin];
    const unsigned chunk = (cntb + SSL - 1) / SSL;
    unsigned r0 = (unsigned)sl * chunk;
    unsigned r1 = r0 + chunk;
    if (r0 > cntb) r0 = cntb;
    if (r1 > cntb) r1 = cntb;
#pragma unroll 4
    for (unsigned r = r0 + threadIdx.x; r < r1; r += TPB) {
        uint2 w = rec[(size_t)base + r];
        unsigned lid = w.y >> 16;
        float fx = __half2float(__ushort_as_half((unsigned short)(w.x & 0xffffu)));
        float fy = __half2float(__ushort_as_half((unsigned short)(w.x >> 16)));
        float fz = __half2float(__ushort_as_half((unsigned short)(w.y & 0xffffu)));
        atomicAdd(&lf[lid * 3 + 0], __float2int_rn(fx * FSCALE));
        atomicAdd(&lf[lid * 3 + 1], __float2int_rn(fy * FSCALE));
        atomicAdd(&lf[lid * 3 + 2], __float2int_rn(fz * FSCALE));
    }
    __syncthreads();
    float4* dst = (float4*)(bpart + (size_t)blockIdx.x * (BINSZ * 3));
    for (int t = threadIdx.x; t < BINSZ * 3 / 4; t += TPB) {
        int4 v = lf4[t];
        dst[t] = make_float4((float)v.x * FINV, (float)v.y * FINV,
                             (float)v.z * FINV, (float)v.w * FINV);
    }
}

// ------------------------------------------------------------- C: force out
__global__ __launch_bounds__(TPB) void force_kernel(
    const float* __restrict__ bpart, const float* __restrict__ pos_grad,
    float* __restrict__ force, long n3) {
    long j = (long)blockIdx.x * TPB + threadIdx.x;
    const long gs = (long)gridDim.x * TPB;
    for (; j < n3; j += gs) {
        unsigned i = (unsigned)(j / 3);
        unsigned c = (unsigned)(j - 3L * i);
        unsigned bin = i >> BIN_SHIFT;
        unsigned lid = i & (BINSZ - 1);
        float acc = -pos_grad[j];
        size_t tb = (size_t)bin * SSL * (BINSZ * 3) + lid * 3 + c;
#pragma unroll
        for (int sl = 0; sl < SSL; ++sl)
            acc += bpart[tb + (size_t)sl * (BINSZ * 3)];
        force[j] = acc;
    }
}

// ------------------------------------------------------------- R: stress out
__global__ __launch_bounds__(TPB) void stress_kernel(
    const float* __restrict__ apart,
    const float* __restrict__ cell_grad, const float* __restrict__ les_cell,
    const float* __restrict__ vol, float* __restrict__ stress, int slots) {
    int t = blockIdx.x;
    if (t >= slots) return;
    __shared__ float red[TPB];
    float s = 0.f;
    const float* row = apart + (size_t)t * NBLKC;
    for (int j = threadIdx.x; j < NBLKC; j += TPB) s += row[j];
    red[threadIdx.x] = s;
    __syncthreads();
    for (int w = TPB / 2; w > 0; w >>= 1) {
        if (threadIdx.x < w) red[threadIdx.x] += red[threadIdx.x + w];
        __syncthreads();
    }
    if (threadIdx.x == 0) {
        int g = t / 6, c = t - 6 * g;
        const int va[6] = {0, 1, 2, 0, 1, 0};
        const int vb[6] = {0, 1, 2, 1, 2, 2};
        int a = va[c], bb = vb[c];
        const float* L = les_cell + 9 * g;
        const float* Gm = cell_grad + 9 * g;
        float lr = L[a] * Gm[bb] + L[3 + a] * Gm[3 + bb] + L[6 + a] * Gm[6 + bb];
        stress[t] = (-red[0] - lr) / vol[g];
    }
}

// ---------------------------------------------------- fallback (round-1 path)
__global__ void init_force_kernel(const float4* __restrict__ pg4,
                                  float4* __restrict__ f4, int n4,
                                  const float* __restrict__ pg,
                                  float* __restrict__ f, int n) {
    int i = blockIdx.x * blockDim.x + threadIdx.x;
    int s = gridDim.x * blockDim.x;
    for (int k = i; k < n4; k += s) {
        float4 v = pg4[k];
        f4[k] = make_float4(-v.x, -v.y, -v.z, -v.w);
    }
    for (int k = n4 * 4 + i; k < n; k += s) f[k] = -pg[k];
}

__global__ __launch_bounds__(256) void edge_dev_kernel(
    const float* __restrict__ rij, const float* __restrict__ fij,
    const int* __restrict__ idx0, const int* __restrict__ idx1,
    const int* __restrict__ batch,
    float* __restrict__ force, float* __restrict__ partials, int E) {
    __shared__ float s_acc[SLOTS];
    for (int t = threadIdx.x; t < SLOTS; t += blockDim.x) s_acc[t] = 0.0f;
    __syncthreads();
    const int stride = gridDim.x * blockDim.x;
    const int tid0 = blockIdx.x * blockDim.x + threadIdx.x;
    for (int e = tid0; e < E; e += stride) {
        float ex = rij[3 * e], ey = rij[3 * e + 1], ez = rij[3 * e + 2];
        float gx = fij[3 * e], gy = fij[3 * e + 1], gz = fij[3 * e + 2];
        int si = idx0[e], ri = idx1[e];
        atomicAdd(&force[3 * si + 0], gx);
        atomicAdd(&force[3 * si + 1], gy);
        atomicAdd(&force[3 * si + 2], gz);
        atomicAdd(&force[3 * ri + 0], -gx);
        atomicAdd(&force[3 * ri + 1], -gy);
        atomicAdd(&force[3 * ri + 2], -gz);
        int g = batch[ri];
        float* a = &s_acc[6 * g];
        atomicAdd(&a[0], ex * gx);
        atomicAdd(&a[1], ey * gy);
        atomicAdd(&a[2], ez * gz);
        atomicAdd(&a[3], ex * gy);
        atomicAdd(&a[4], ey * gz);
        atomicAdd(&a[5], ez * gx);
    }
    __syncthreads();
    for (int t = threadIdx.x; t < SLOTS; t += blockDim.x)
        partials[(size_t)blockIdx.x * SLOTS + t] = s_acc[t];
}

__global__ void reduce_finalize_kernel(const float* __restrict__ partials, int nblocks,
                                       const float* __restrict__ cell_grad,
                                       const float* __restrict__ les_cell,
                                       const float* __restrict__ vol,
                                       float* __restrict__ stress_out, int slots) {
    int t = blockIdx.x * blockDim.x + threadIdx.x;
    if (t >= slots) return;
    float s = 0.0f;
    for (int b = 0; b < nblocks; ++b) s += partials[(size_t)b * SLOTS + t];
    int g = t / 6, c = t - 6 * g;
    const int va[6] = {0, 1, 2, 0, 1, 0};
    const int vb[6] = {0, 1, 2, 1, 2, 2};
    int a = va[c], bb = vb[c];
    const float* L = les_cell + 9 * g;
    const float* G = cell_grad + 9 * g;
    float lr = L[a] * G[bb] + L[3 + a] * G[3 + bb] + L[6 + a] * G[6 + bb];
    stress_out[t] = (-s - lr) / vol[g];
}

// ------------------------------------------------------------------ launcher
static inline size_t alignup(size_t x) { return (x + 255) & ~(size_t)255; }

extern "C" void kernel_launch(void* const* d_in, const int* in_sizes, int n_in,
                              void* d_out, int out_size, void* d_ws, size_t ws_size,
                              hipStream_t stream) {
    const float* rij = (const float*)d_in[0];
    const float* fij = (const float*)d_in[1];
    const float* pos_grad = (const float*)d_in[2];
    const float* cell_grad = (const float*)d_in[3];
    const float* les_cell = (const float*)d_in[4];
    const float* vol = (const float*)d_in[5];
    const int* edge_idx = (const int*)d_in[6];
    const int* batch = (const int*)d_in[7];

    const int E = in_sizes[0] / 3;
    const int N = in_sizes[2] / 3;
    const int ngr = in_sizes[5];
    const int slots = 6 * ngr;

    float* force = (float*)d_out;
    float* stress = (float*)d_out + (size_t)N * 3;

    const int nbins = (N + BINSZ - 1) >> BIN_SHIFT;
    const long N3 = (long)N * 3;

    // workspace layout
    size_t off = 0;
    const size_t o_rec = off;   off += alignup((size_t)2 * E * 8);
    const size_t o_hist = off;  off += alignup((size_t)MAXB * NBLKC * 4);
    const size_t o_base = off;  off += alignup(MAXB * 4);
    const size_t o_cnt = off;   off += alignup(MAXB * 4);
    const size_t o_cur = off;   off += alignup(MAXB * 4);
    const size_t o_apart = off; off += alignup((size_t)SLOTS * NBLKC * 4);
    const size_t o_bpart = off; off += alignup((size_t)nbins * SSL * (BINSZ * 3) * 4);
    const bool fit = (off <= ws_size) && (nbins <= MAXB) && (ngr <= MAXG) && (E >= 4);

    if (fit) {
        char* ws = (char*)d_ws;
        uint2* rec = (uint2*)(ws + o_rec);
        unsigned* g_hist = (unsigned*)(ws + o_hist);
        unsigned* bin_base = (unsigned*)(ws + o_base);
        unsigned* bin_count = (unsigned*)(ws + o_cnt);
        unsigned* cursor = (unsigned*)(ws + o_cur);
        float* apart = (float*)(ws + o_apart);
        float* bpart = (float*)(ws + o_bpart);

        count_kernel<<<NBLKC, TPB, 0, stream>>>(
            rij, fij, edge_idx, edge_idx + E, batch, g_hist, apart, E, nbins);
        scan_kernel<<<1, TPB, 0, stream>>>(g_hist, bin_base, bin_count, cursor, nbins);

        const size_t smem = (size_t)nbins * CAP * 8 + (size_t)nbins * 8;
        scatter_kernel<<<NBLKS, TPB, smem, stream>>>(
            fij, edge_idx, edge_idx + E, cursor, rec, E, nbins);

        bin_accum_kernel<<<nbins * SSL, TPB, 0, stream>>>(
            rec, bin_base, bin_count, bpart);

        int fblocks = (int)((N3 + TPB - 1) / TPB);
        if (fblocks > 4096) fblocks = 4096;
        force_kernel<<<fblocks, TPB, 0, stream>>>(bpart, pos_grad, force, N3);

        stress_kernel<<<slots, TPB, 0, stream>>>(apart, cell_grad, les_cell, vol,
                                                 stress, slots);
    } else {
        // device-atomic fallback (proven correct, slow)
        float* partials = (float*)d_ws;
        int eblocks = 512;
        size_t need = (size_t)eblocks * SLOTS * sizeof(float);
        if (need > ws_size) {
            int fit2 = (int)(ws_size / (SLOTS * sizeof(float)));
            eblocks = fit2 > 0 ? fit2 : 1;
        }
        int n = (int)N3, n4 = n / 4;
        int blocks = (n4 + 255) / 256;
        if (blocks > 1024) blocks = 1024;
        if (blocks < 1) blocks = 1;
        init_force_kernel<<<blocks, 256, 0, stream>>>(
            (const float4*)pos_grad, (float4*)force, n4, pos_grad, force, n);
        edge_dev_kernel<<<eblocks, 256, 0, stream>>>(rij, fij, edge_idx, edge_idx + E,
                                                     batch, force, partials, E);
        reduce_finalize_kernel<<<6, 64, 0, stream>>>(partials, eblocks, cell_grad,
                                                     les_cell, vol, stress, slots);
    }
}

// Round 11
// 319.901 us; speedup vs baseline: 2.0282x; 1.0235x over previous
//
#include <hip/hip_runtime.h>
#include <hip/hip_fp16.h>

static constexpr int TPB       = 256;
static constexpr int MAXB      = 64;            // max super-bins (N <= 256K at 4096/bin)
static constexpr int BIN_SHIFT = 12;            // 4096-node staging/record super-bin
static constexpr int BINSZ     = 1 << BIN_SHIFT;
static constexpr int SUB_SHIFT = 11;            // 2048-node accum subtile (24KB int LDS)
static constexpr int SUBSZ     = 1 << SUB_SHIFT;
static constexpr int NSUB      = BINSZ / SUBSZ; // 2
static constexpr int CAP       = 64;            // LDS bucket depth per super-bin
static constexpr int NBLKS     = 2048;          // scatter blocks
static constexpr int NBLKC     = 1024;          // count blocks
static constexpr int SSL       = 16;            // record slices per (bin,subtile)
static constexpr int MAXG      = 64;
static constexpr int SLOTS     = MAXG * 6;      // 384 stress accumulators
static constexpr int NWAVES    = TPB / 64;

static constexpr float VSCALE  = 4096.0f;       // virial fixed-point (2^12)
static constexpr float VINV    = 1.0f / 4096.0f;
static constexpr float FSCALE  = 1048576.0f;    // force fixed-point (2^20)
static constexpr float FINV    = 1.0f / 1048576.0f;

// -------------------------------------- A1: count + virial (streaming pass)
__global__ __launch_bounds__(TPB) void count_kernel(
    const float* __restrict__ rij, const float* __restrict__ fij,
    const int* __restrict__ idx0, const int* __restrict__ idx1,
    const int* __restrict__ batch,
    unsigned* __restrict__ g_hist, float* __restrict__ apart,
    int E, int nbins) {
    __shared__ unsigned hist[MAXB];
    __shared__ int s_acc[SLOTS];
    for (int t = threadIdx.x; t < nbins; t += TPB) hist[t] = 0u;
    for (int t = threadIdx.x; t < SLOTS; t += TPB) s_acc[t] = 0;
    __syncthreads();

    const int NG = E >> 2;
    const int GC = (NG + NBLKC - 1) / NBLKC;
    const int g0 = blockIdx.x * GC;
    int g1 = g0 + GC; if (g1 > NG) g1 = NG;
    const int4* i04 = (const int4*)idx0;
    const int4* i14 = (const int4*)idx1;
    const float4* rij4 = (const float4*)rij;
    const float4* fij4 = (const float4*)fij;

    for (int k = g0 + threadIdx.x; k < g1; k += TPB) {
        int4 a = i04[k], b = i14[k];
        atomicAdd(&hist[((unsigned)a.x) >> BIN_SHIFT], 1u);
        atomicAdd(&hist[((unsigned)a.y) >> BIN_SHIFT], 1u);
        atomicAdd(&hist[((unsigned)a.z) >> BIN_SHIFT], 1u);
        atomicAdd(&hist[((unsigned)a.w) >> BIN_SHIFT], 1u);
        atomicAdd(&hist[((unsigned)b.x) >> BIN_SHIFT], 1u);
        atomicAdd(&hist[((unsigned)b.y) >> BIN_SHIFT], 1u);
        atomicAdd(&hist[((unsigned)b.z) >> BIN_SHIFT], 1u);
        atomicAdd(&hist[((unsigned)b.w) >> BIN_SHIFT], 1u);

        float4 fa = fij4[3 * k], fb = fij4[3 * k + 1], fc = fij4[3 * k + 2];
        float4 ra = rij4[3 * k], rb = rij4[3 * k + 1], rc = rij4[3 * k + 2];
        float fx[4] = {fa.x, fa.w, fb.z, fc.y};
        float fy[4] = {fa.y, fb.x, fb.w, fc.z};
        float fz[4] = {fa.z, fb.y, fc.x, fc.w};
        float rx[4] = {ra.x, ra.w, rb.z, rc.y};
        float ry[4] = {ra.y, rb.x, rb.w, rc.z};
        float rz[4] = {ra.z, rb.y, rc.x, rc.w};
        int r[4] = {b.x, b.y, b.z, b.w};
#pragma unroll
        for (int e = 0; e < 4; ++e) {
            int g = batch[r[e]];
            int* s = &s_acc[6 * g];
            atomicAdd(&s[0], __float2int_rn(rx[e] * fx[e] * VSCALE));
            atomicAdd(&s[1], __float2int_rn(ry[e] * fy[e] * VSCALE));
            atomicAdd(&s[2], __float2int_rn(rz[e] * fz[e] * VSCALE));
            atomicAdd(&s[3], __float2int_rn(rx[e] * fy[e] * VSCALE));
            atomicAdd(&s[4], __float2int_rn(ry[e] * fz[e] * VSCALE));
            atomicAdd(&s[5], __float2int_rn(rz[e] * fx[e] * VSCALE));
        }
    }
    if (blockIdx.x == 0) {  // scalar tail (E % 4)
        for (int e = (NG << 2) + threadIdx.x; e < E; e += TPB) {
            atomicAdd(&hist[((unsigned)idx0[e]) >> BIN_SHIFT], 1u);
            atomicAdd(&hist[((unsigned)idx1[e]) >> BIN_SHIFT], 1u);
            float ex = rij[3 * e], ey = rij[3 * e + 1], ez = rij[3 * e + 2];
            float gx = fij[3 * e], gy = fij[3 * e + 1], gz = fij[3 * e + 2];
            int g = batch[idx1[e]];
            int* s = &s_acc[6 * g];
            atomicAdd(&s[0], __float2int_rn(ex * gx * VSCALE));
            atomicAdd(&s[1], __float2int_rn(ey * gy * VSCALE));
            atomicAdd(&s[2], __float2int_rn(ez * gz * VSCALE));
            atomicAdd(&s[3], __float2int_rn(ex * gy * VSCALE));
            atomicAdd(&s[4], __float2int_rn(ey * gz * VSCALE));
            atomicAdd(&s[5], __float2int_rn(ez * gx * VSCALE));
        }
    }
    __syncthreads();
    for (int t = threadIdx.x; t < nbins; t += TPB)
        g_hist[(size_t)t * NBLKC + blockIdx.x] = hist[t];
    for (int t = threadIdx.x; t < SLOTS; t += TPB)
        apart[(size_t)t * NBLKC + blockIdx.x] = (float)s_acc[t] * VINV;
}

// ------------------------------------------- SCAN: bin totals/bases (1 block)
__global__ __launch_bounds__(TPB) void scan_kernel(
    const unsigned* __restrict__ g_hist,
    unsigned* __restrict__ bin_base, unsigned* __restrict__ bin_count,
    unsigned* __restrict__ cursor, int nbins) {
    __shared__ unsigned part[TPB];
    __shared__ unsigned tot[MAXB], base[MAXB];
    int b = threadIdx.x >> 2, q = threadIdx.x & 3;
    unsigned s = 0;
    if (b < nbins)
        for (int j = q; j < NBLKC; j += 4) s += g_hist[(size_t)b * NBLKC + j];
    part[threadIdx.x] = s;
    __syncthreads();
    if (threadIdx.x < (unsigned)nbins) {
        int t4 = threadIdx.x * 4;
        tot[threadIdx.x] = part[t4] + part[t4 + 1] + part[t4 + 2] + part[t4 + 3];
    }
    __syncthreads();
    if (threadIdx.x == 0) {
        unsigned run = 0;
        for (int i = 0; i < nbins; ++i) { base[i] = run; run += tot[i]; }
    }
    __syncthreads();
    if (threadIdx.x < (unsigned)nbins) {
        bin_base[threadIdx.x] = base[threadIdx.x];
        bin_count[threadIdx.x] = tot[threadIdx.x];
        cursor[threadIdx.x] = base[threadIdx.x];
    }
}

// ------------------------------------------------------------- A3: scatter
__device__ inline uint2 pack_rec(int node, float fx, float fy, float fz) {
    unsigned lid = (unsigned)node & (BINSZ - 1);    // 12-bit local id
    unsigned w0 = (unsigned)__half_as_ushort(__float2half(fx)) |
                  ((unsigned)__half_as_ushort(__float2half(fy)) << 16);
    unsigned w1 = (unsigned)__half_as_ushort(__float2half(fz)) | (lid << 16);
    return make_uint2(w0, w1);
}

__device__ inline void emit(uint2* __restrict__ rec, unsigned* __restrict__ cursor,
                            unsigned* __restrict__ cnt, uint2* __restrict__ buf,
                            int node, float fx, float fy, float fz) {
    int b = node >> BIN_SHIFT;
    uint2 w = pack_rec(node, fx, fy, fz);
    unsigned slot = atomicAdd(&cnt[b], 1u);
    if (slot < (unsigned)CAP) buf[b * CAP + slot] = w;
    else { unsigned d = atomicAdd(&cursor[b], 1u); rec[d] = w; }  // rare overflow
}

__global__ __launch_bounds__(TPB) void scatter_kernel(
    const float* __restrict__ fij,
    const int* __restrict__ idx0, const int* __restrict__ idx1,
    unsigned* __restrict__ cursor, uint2* __restrict__ rec,
    int E, int nbins) {
    extern __shared__ char smem[];
    uint2* buf = (uint2*)smem;                                   // nbins*CAP (25KB)
    unsigned* cnt = (unsigned*)(buf + (size_t)nbins * CAP);      // nbins
    unsigned* base_s = cnt + nbins;                              // nbins

    for (int t = threadIdx.x; t < nbins; t += TPB) cnt[t] = 0u;
    __syncthreads();

    const int NG = E >> 2;
    const int GC = (NG + NBLKS - 1) / NBLKS;
    const int g0 = blockIdx.x * GC;
    int g1 = g0 + GC; if (g1 > NG) g1 = NG;
    const int span = g1 - g0;
    const int niter = span > 0 ? (span + TPB - 1) / TPB : 0;

    const float4* fij4 = (const float4*)fij;
    const int4* i04 = (const int4*)idx0;
    const int4* i14 = (const int4*)idx1;

    const int wid = threadIdx.x >> 6, lane = threadIdx.x & 63;

    for (int it = 0; it < niter; ++it) {
        int k = g0 + it * TPB + threadIdx.x;
        if (k < g1) {
            float4 fa = fij4[3 * k], fb = fij4[3 * k + 1], fc = fij4[3 * k + 2];
            int4 i0 = i04[k], i1 = i14[k];
            float fx[4] = {fa.x, fa.w, fb.z, fc.y};
            float fy[4] = {fa.y, fb.x, fb.w, fc.z};
            float fz[4] = {fa.z, fb.y, fc.x, fc.w};
            int s[4] = {i0.x, i0.y, i0.z, i0.w};
            int r[4] = {i1.x, i1.y, i1.z, i1.w};
#pragma unroll
            for (int e = 0; e < 4; ++e) {
                emit(rec, cursor, cnt, buf, s[e], fx[e], fy[e], fz[e]);
                emit(rec, cursor, cnt, buf, r[e], -fx[e], -fy[e], -fz[e]);
            }
        }
        __syncthreads();
        // F1: bulk slot reservation — one parallel vector atomic (lanes = bins)
        if (threadIdx.x < (unsigned)nbins) {
            unsigned c = cnt[threadIdx.x];
            unsigned m = c < (unsigned)CAP ? c : (unsigned)CAP;
            base_s[threadIdx.x] = m ? atomicAdd(&cursor[threadIdx.x], m) : 0u;
        }
        __syncthreads();
        // F2: coalesced wave flush (~12 bins/wave at 49 super-bins, ~66% lane util)
        for (int b = wid; b < nbins; b += NWAVES) {
            unsigned c = cnt[b];
            unsigned m = c < (unsigned)CAP ? c : (unsigned)CAP;
            if ((unsigned)lane < m) rec[base_s[b] + lane] = buf[b * CAP + lane];
            if (lane == 0) cnt[b] = 0u;
        }
        __syncthreads();
    }

    // scalar tail (E % 4): block 0, direct reservation
    if (blockIdx.x == 0) {
        for (int e = (NG << 2) + threadIdx.x; e < E; e += TPB) {
            float gx = fij[3 * e], gy = fij[3 * e + 1], gz = fij[3 * e + 2];
            int si = idx0[e], ri = idx1[e];
            unsigned d0 = atomicAdd(&cursor[si >> BIN_SHIFT], 1u);
            rec[d0] = pack_rec(si, gx, gy, gz);
            unsigned d1 = atomicAdd(&cursor[ri >> BIN_SHIFT], 1u);
            rec[d1] = pack_rec(ri, -gx, -gy, -gz);
        }
    }
}

// ------------------------------------------------------------- B: accumulate
__global__ __launch_bounds__(TPB) void bin_accum_kernel(
    const uint2* __restrict__ rec,
    const unsigned* __restrict__ bin_base, const unsigned* __restrict__ bin_count,
    float* __restrict__ bpart) {
    __shared__ int lf[SUBSZ * 3];                      // 24KB, fixed-point 2^20
    const int sl = blockIdx.x % SSL;
    const int r2 = blockIdx.x / SSL;
    const int st = r2 & (NSUB - 1);
    const int bin = r2 >> 1;                           // NSUB == 2

    int4* lf4 = (int4*)lf;
    for (int t = threadIdx.x; t < SUBSZ * 3 / 4; t += TPB)
        lf4[t] = make_int4(0, 0, 0, 0);
    __syncthreads();

    const unsigned base = bin_base[bin], cntb = bin_count[bin];
    const unsigned chunk = (cntb + SSL - 1) / SSL;
    unsigned r0 = (unsigned)sl * chunk;
    unsigned r1 = r0 + chunk;
    if (r0 > cntb) r0 = cntb;
    if (r1 > cntb) r1 = cntb;
#pragma unroll 4
    for (unsigned r = r0 + threadIdx.x; r < r1; r += TPB) {
        uint2 w = rec[(size_t)base + r];
        unsigned lid = w.y >> 16;
        if ((int)(lid >> SUB_SHIFT) == st) {
            unsigned l2 = lid & (SUBSZ - 1);
            float fx = __half2float(__ushort_as_half((unsigned short)(w.x & 0xffffu)));
            float fy = __half2float(__ushort_as_half((unsigned short)(w.x >> 16)));
            float fz = __half2float(__ushort_as_half((unsigned short)(w.y & 0xffffu)));
            atomicAdd(&lf[l2 * 3 + 0], __float2int_rn(fx * FSCALE));
            atomicAdd(&lf[l2 * 3 + 1], __float2int_rn(fy * FSCALE));
            atomicAdd(&lf[l2 * 3 + 2], __float2int_rn(fz * FSCALE));
        }
    }
    __syncthreads();
    float4* dst = (float4*)(bpart + (size_t)blockIdx.x * (SUBSZ * 3));
    for (int t = threadIdx.x; t < SUBSZ * 3 / 4; t += TPB) {
        int4 v = lf4[t];
        dst[t] = make_float4((float)v.x * FINV, (float)v.y * FINV,
                             (float)v.z * FINV, (float)v.w * FINV);
    }
}

// ------------------------------------------------------------- C: force out
__global__ __launch_bounds__(TPB) void force_kernel(
    const float* __restrict__ bpart, const float* __restrict__ pos_grad,
    float* __restrict__ force, long n3) {
    long j = (long)blockIdx.x * TPB + threadIdx.x;
    const long gs = (long)gridDim.x * TPB;
    for (; j < n3; j += gs) {
        unsigned i = (unsigned)(j / 3);
        unsigned c = (unsigned)(j - 3L * i);
        unsigned bin = i >> BIN_SHIFT;
        unsigned st = (i >> SUB_SHIFT) & (NSUB - 1);
        unsigned l2 = i & (SUBSZ - 1);
        float acc = -pos_grad[j];
        size_t tb = ((size_t)(bin * NSUB + st) * SSL) * (SUBSZ * 3) + l2 * 3 + c;
#pragma unroll
        for (int sl = 0; sl < SSL; ++sl)
            acc += bpart[tb + (size_t)sl * (SUBSZ * 3)];
        force[j] = acc;
    }
}

// ------------------------------------------------------------- R: stress out
__global__ __launch_bounds__(TPB) void stress_kernel(
    const float* __restrict__ apart,
    const float* __restrict__ cell_grad, const float* __restrict__ les_cell,
    const float* __restrict__ vol, float* __restrict__ stress, int slots) {
    int t = blockIdx.x;
    if (t >= slots) return;
    __shared__ float red[TPB];
    float s = 0.f;
    const float* row = apart + (size_t)t * NBLKC;
    for (int j = threadIdx.x; j < NBLKC; j += TPB) s += row[j];
    red[threadIdx.x] = s;
    __syncthreads();
    for (int w = TPB / 2; w > 0; w >>= 1) {
        if (threadIdx.x < w) red[threadIdx.x] += red[threadIdx.x + w];
        __syncthreads();
    }
    if (threadIdx.x == 0) {
        int g = t / 6, c = t - 6 * g;
        const int va[6] = {0, 1, 2, 0, 1, 0};
        const int vb[6] = {0, 1, 2, 1, 2, 2};
        int a = va[c], bb = vb[c];
        const float* L = les_cell + 9 * g;
        const float* Gm = cell_grad + 9 * g;
        float lr = L[a] * Gm[bb] + L[3 + a] * Gm[3 + bb] + L[6 + a] * Gm[6 + bb];
        stress[t] = (-red[0] - lr) / vol[g];
    }
}

// ---------------------------------------------------- fallback (round-1 path)
__global__ void init_force_kernel(const float4* __restrict__ pg4,
                                  float4* __restrict__ f4, int n4,
                                  const float* __restrict__ pg,
                                  float* __restrict__ f, int n) {
    int i = blockIdx.x * blockDim.x + threadIdx.x;
    int s = gridDim.x * blockDim.x;
    for (int k = i; k < n4; k += s) {
        float4 v = pg4[k];
        f4[k] = make_float4(-v.x, -v.y, -v.z, -v.w);
    }
    for (int k = n4 * 4 + i; k < n; k += s) f[k] = -pg[k];
}

__global__ __launch_bounds__(256) void edge_dev_kernel(
    const float* __restrict__ rij, const float* __restrict__ fij,
    const int* __restrict__ idx0, const int* __restrict__ idx1,
    const int* __restrict__ batch,
    float* __restrict__ force, float* __restrict__ partials, int E) {
    __shared__ float s_acc[SLOTS];
    for (int t = threadIdx.x; t < SLOTS; t += blockDim.x) s_acc[t] = 0.0f;
    __syncthreads();
    const int stride = gridDim.x * blockDim.x;
    const int tid0 = blockIdx.x * blockDim.x + threadIdx.x;
    for (int e = tid0; e < E; e += stride) {
        float ex = rij[3 * e], ey = rij[3 * e + 1], ez = rij[3 * e + 2];
        float gx = fij[3 * e], gy = fij[3 * e + 1], gz = fij[3 * e + 2];
        int si = idx0[e], ri = idx1[e];
        atomicAdd(&force[3 * si + 0], gx);
        atomicAdd(&force[3 * si + 1], gy);
        atomicAdd(&force[3 * si + 2], gz);
        atomicAdd(&force[3 * ri + 0], -gx);
        atomicAdd(&force[3 * ri + 1], -gy);
        atomicAdd(&force[3 * ri + 2], -gz);
        int g = batch[ri];
        float* a = &s_acc[6 * g];
        atomicAdd(&a[0], ex * gx);
        atomicAdd(&a[1], ey * gy);
        atomicAdd(&a[2], ez * gz);
        atomicAdd(&a[3], ex * gy);
        atomicAdd(&a[4], ey * gz);
        atomicAdd(&a[5], ez * gx);
    }
    __syncthreads();
    for (int t = threadIdx.x; t < SLOTS; t += blockDim.x)
        partials[(size_t)blockIdx.x * SLOTS + t] = s_acc[t];
}

__global__ void reduce_finalize_kernel(const float* __restrict__ partials, int nblocks,
                                       const float* __restrict__ cell_grad,
                                       const float* __restrict__ les_cell,
                                       const float* __restrict__ vol,
                                       float* __restrict__ stress_out, int slots) {
    int t = blockIdx.x * blockDim.x + threadIdx.x;
    if (t >= slots) return;
    float s = 0.0f;
    for (int b = 0; b < nblocks; ++b) s += partials[(size_t)b * SLOTS + t];
    int g = t / 6, c = t - 6 * g;
    const int va[6] = {0, 1, 2, 0, 1, 0};
    const int vb[6] = {0, 1, 2, 1, 2, 2};
    int a = va[c], bb = vb[c];
    const float* L = les_cell + 9 * g;
    const float* G = cell_grad + 9 * g;
    float lr = L[a] * G[bb] + L[3 + a] * G[3 + bb] + L[6 + a] * G[6 + bb];
    stress_out[t] = (-s - lr) / vol[g];
}

// ------------------------------------------------------------------ launcher
static inline size_t alignup(size_t x) { return (x + 255) & ~(size_t)255; }

extern "C" void kernel_launch(void* const* d_in, const int* in_sizes, int n_in,
                              void* d_out, int out_size, void* d_ws, size_t ws_size,
                              hipStream_t stream) {
    const float* rij = (const float*)d_in[0];
    const float* fij = (const float*)d_in[1];
    const float* pos_grad = (const float*)d_in[2];
    const float* cell_grad = (const float*)d_in[3];
    const float* les_cell = (const float*)d_in[4];
    const float* vol = (const float*)d_in[5];
    const int* edge_idx = (const int*)d_in[6];
    const int* batch = (const int*)d_in[7];

    const int E = in_sizes[0] / 3;
    const int N = in_sizes[2] / 3;
    const int ngr = in_sizes[5];
    const int slots = 6 * ngr;

    float* force = (float*)d_out;
    float* stress = (float*)d_out + (size_t)N * 3;

    const int nbins = (N + BINSZ - 1) >> BIN_SHIFT;
    const long N3 = (long)N * 3;

    // workspace layout
    size_t off = 0;
    const size_t o_rec = off;   off += alignup((size_t)2 * E * 8);
    const size_t o_hist = off;  off += alignup((size_t)MAXB * NBLKC * 4);
    const size_t o_base = off;  off += alignup(MAXB * 4);
    const size_t o_cnt = off;   off += alignup(MAXB * 4);
    const size_t o_cur = off;   off += alignup(MAXB * 4);
    const size_t o_apart = off; off += alignup((size_t)SLOTS * NBLKC * 4);
    const size_t o_bpart = off; off += alignup((size_t)nbins * NSUB * SSL * (SUBSZ * 3) * 4);
    const bool fit = (off <= ws_size) && (nbins <= MAXB) && (ngr <= MAXG) && (E >= 4);

    if (fit) {
        char* ws = (char*)d_ws;
        uint2* rec = (uint2*)(ws + o_rec);
        unsigned* g_hist = (unsigned*)(ws + o_hist);
        unsigned* bin_base = (unsigned*)(ws + o_base);
        unsigned* bin_count = (unsigned*)(ws + o_cnt);
        unsigned* cursor = (unsigned*)(ws + o_cur);
        float* apart = (float*)(ws + o_apart);
        float* bpart = (float*)(ws + o_bpart);

        count_kernel<<<NBLKC, TPB, 0, stream>>>(
            rij, fij, edge_idx, edge_idx + E, batch, g_hist, apart, E, nbins);
        scan_kernel<<<1, TPB, 0, stream>>>(g_hist, bin_base, bin_count, cursor, nbins);

        const size_t smem = (size_t)nbins * CAP * 8 + (size_t)nbins * 8;
        scatter_kernel<<<NBLKS, TPB, smem, stream>>>(
            fij, edge_idx, edge_idx + E, cursor, rec, E, nbins);

        bin_accum_kernel<<<nbins * NSUB * SSL, TPB, 0, stream>>>(
            rec, bin_base, bin_count, bpart);

        int fblocks = (int)((N3 + TPB - 1) / TPB);
        if (fblocks > 4096) fblocks = 4096;
        force_kernel<<<fblocks, TPB, 0, stream>>>(bpart, pos_grad, force, N3);

        stress_kernel<<<slots, TPB, 0, stream>>>(apart, cell_grad, les_cell, vol,
                                                 stress, slots);
    } else {
        // device-atomic fallback (proven correct, slow)
        float* partials = (float*)d_ws;
        int eblocks = 512;
        size_t need = (size_t)eblocks * SLOTS * sizeof(float);
        if (need > ws_size) {
            int fit2 = (int)(ws_size / (SLOTS * sizeof(float)));
            eblocks = fit2 > 0 ? fit2 : 1;
        }
        int n = (int)N3, n4 = n / 4;
        int blocks = (n4 + 255) / 256;
        if (blocks > 1024) blocks = 1024;
        if (blocks < 1) blocks = 1;
        init_force_kernel<<<blocks, 256, 0, stream>>>(
            (const float4*)pos_grad, (float4*)force, n4, pos_grad, force, n);
        edge_dev_kernel<<<eblocks, 256, 0, stream>>>(rij, fij, edge_idx, edge_idx + E,
                                                     batch, force, partials, E);
        reduce_finalize_kernel<<<6, 64, 0, stream>>>(partials, eblocks, cell_grad,
                                                     les_cell, vol, stress, slots);
    }
}

// Round 12
// 262.359 us; speedup vs baseline: 2.4730x; 1.2193x over previous
//
#include <hip/hip_runtime.h>
#include <hip/hip_fp16.h>

static constexpr int TPB       = 256;
static constexpr int MAXB      = 64;            // max super-bins (N <= 256K at 4096/bin)
static constexpr int BIN_SHIFT = 12;            // 4096-node staging/record super-bin
static constexpr int BINSZ     = 1 << BIN_SHIFT;
static constexpr int SUB_SHIFT = 11;            // 2048-node accum subtile (24KB int LDS)
static constexpr int SUBSZ     = 1 << SUB_SHIFT;
static constexpr int NSUB      = BINSZ / SUBSZ; // 2
static constexpr int CAP       = 64;            // LDS bucket depth per super-bin
static constexpr int NBLKS     = 2048;          // scatter blocks
static constexpr int SSL       = 16;            // record slices per (bin,subtile)
static constexpr int MAXG      = 64;
static constexpr int SLOTS     = MAXG * 6;      // 384 stress accumulators
static constexpr int NWAVES    = TPB / 64;

static constexpr float VSCALE  = 4096.0f;       // virial fixed-point (2^12)
static constexpr float VINV    = 1.0f / 4096.0f;
static constexpr float FSCALE  = 1048576.0f;    // force fixed-point (2^20)
static constexpr float FINV    = 1.0f / 1048576.0f;

// --------------------------------------------------- cursor init (1 block)
__global__ __launch_bounds__(64) void init_cursor_kernel(
    unsigned* __restrict__ cursor, int nbins, unsigned cap) {
    int b = threadIdx.x;
    if (b < nbins) cursor[b] = (unsigned)b * cap;
}

// --------------------- A: merged scatter + virial (single input streaming)
__device__ inline uint2 pack_rec(int node, float fx, float fy, float fz) {
    unsigned lid = (unsigned)node & (BINSZ - 1);    // 12-bit local id
    unsigned w0 = (unsigned)__half_as_ushort(__float2half(fx)) |
                  ((unsigned)__half_as_ushort(__float2half(fy)) << 16);
    unsigned w1 = (unsigned)__half_as_ushort(__float2half(fz)) | (lid << 16);
    return make_uint2(w0, w1);
}

__global__ __launch_bounds__(TPB) void scatter_kernel(
    const float* __restrict__ rij, const float* __restrict__ fij,
    const int* __restrict__ idx0, const int* __restrict__ idx1,
    const int* __restrict__ batch,
    unsigned* __restrict__ cursor, uint2* __restrict__ rec,
    float* __restrict__ apart,
    int E, int nbins, unsigned limit) {
    extern __shared__ char smem[];
    uint2* buf = (uint2*)smem;                                   // nbins*CAP
    unsigned* cnt = (unsigned*)(buf + (size_t)nbins * CAP);      // nbins
    unsigned* base_s = cnt + nbins;                              // nbins
    int* s_acc = (int*)(base_s + nbins);                         // SLOTS (int)

    for (int t = threadIdx.x; t < nbins; t += TPB) cnt[t] = 0u;
    for (int t = threadIdx.x; t < SLOTS; t += TPB) s_acc[t] = 0;
    __syncthreads();

    const int NG = E >> 2;
    const int GC = (NG + NBLKS - 1) / NBLKS;
    const int g0 = blockIdx.x * GC;
    int g1 = g0 + GC; if (g1 > NG) g1 = NG;
    const int span = g1 - g0;
    const int niter = span > 0 ? (span + TPB - 1) / TPB : 0;

    const float4* fij4 = (const float4*)fij;
    const float4* rij4 = (const float4*)rij;
    const int4* i04 = (const int4*)idx0;
    const int4* i14 = (const int4*)idx1;

    const int wid = threadIdx.x >> 6, lane = threadIdx.x & 63;

    for (int it = 0; it < niter; ++it) {
        int k = g0 + it * TPB + threadIdx.x;
        if (k < g1) {
            float4 fa = fij4[3 * k], fb = fij4[3 * k + 1], fc = fij4[3 * k + 2];
            float4 ra = rij4[3 * k], rb = rij4[3 * k + 1], rc = rij4[3 * k + 2];
            int4 i0 = i04[k], i1 = i14[k];
            float fx[4] = {fa.x, fa.w, fb.z, fc.y};
            float fy[4] = {fa.y, fb.x, fb.w, fc.z};
            float fz[4] = {fa.z, fb.y, fc.x, fc.w};
            float rx[4] = {ra.x, ra.w, rb.z, rc.y};
            float ry[4] = {ra.y, rb.x, rb.w, rc.z};
            float rz[4] = {ra.z, rb.y, rc.x, rc.w};
            int s[4] = {i0.x, i0.y, i0.z, i0.w};
            int r[4] = {i1.x, i1.y, i1.z, i1.w};

            // two-phase emit: pack all 8, issue all 8 atomics, then all stores
            int bb[8]; uint2 wv[8]; unsigned slot[8];
#pragma unroll
            for (int e = 0; e < 4; ++e) {
                bb[2 * e] = s[e] >> BIN_SHIFT;
                wv[2 * e] = pack_rec(s[e], fx[e], fy[e], fz[e]);
                bb[2 * e + 1] = r[e] >> BIN_SHIFT;
                wv[2 * e + 1] = pack_rec(r[e], -fx[e], -fy[e], -fz[e]);
            }
#pragma unroll
            for (int j = 0; j < 8; ++j)
                slot[j] = atomicAdd(&cnt[bb[j]], 1u);
#pragma unroll
            for (int j = 0; j < 8; ++j) {
                if (slot[j] < (unsigned)CAP) {
                    buf[bb[j] * CAP + slot[j]] = wv[j];
                } else {
                    unsigned d = atomicAdd(&cursor[bb[j]], 1u);
                    if (d >= limit) d = limit - 1;   // guard (statistically unreachable)
                    rec[d] = wv[j];
                }
            }
            // virial (int fixed-point LDS atomics — single-instruction ds_add)
#pragma unroll
            for (int e = 0; e < 4; ++e) {
                int g = batch[r[e]];
                int* a = &s_acc[6 * g];
                atomicAdd(&a[0], __float2int_rn(rx[e] * fx[e] * VSCALE));
                atomicAdd(&a[1], __float2int_rn(ry[e] * fy[e] * VSCALE));
                atomicAdd(&a[2], __float2int_rn(rz[e] * fz[e] * VSCALE));
                atomicAdd(&a[3], __float2int_rn(rx[e] * fy[e] * VSCALE));
                atomicAdd(&a[4], __float2int_rn(ry[e] * fz[e] * VSCALE));
                atomicAdd(&a[5], __float2int_rn(rz[e] * fx[e] * VSCALE));
            }
        }
        __syncthreads();
        // F1: bulk slot reservation — one parallel vector atomic (lanes = bins)
        if (threadIdx.x < (unsigned)nbins) {
            unsigned c = cnt[threadIdx.x];
            unsigned m = c < (unsigned)CAP ? c : (unsigned)CAP;
            base_s[threadIdx.x] = m ? atomicAdd(&cursor[threadIdx.x], m) : 0u;
        }
        __syncthreads();
        // F2: coalesced wave flush + fold counter zeroing into the same pass
        for (int b = wid; b < nbins; b += NWAVES) {
            unsigned c = cnt[b];
            unsigned m = c < (unsigned)CAP ? c : (unsigned)CAP;
            if ((unsigned)lane < m) {
                unsigned d = base_s[b] + lane;
                if (d >= limit) d = limit - 1;
                rec[d] = buf[b * CAP + lane];
            }
            if (lane == 0) cnt[b] = 0u;
        }
        __syncthreads();
    }

    // scalar tail (E % 4): block 0, direct reservation + virial
    if (blockIdx.x == 0) {
        for (int e = (NG << 2) + threadIdx.x; e < E; e += TPB) {
            float gx = fij[3 * e], gy = fij[3 * e + 1], gz = fij[3 * e + 2];
            int si = idx0[e], ri = idx1[e];
            unsigned d0 = atomicAdd(&cursor[si >> BIN_SHIFT], 1u);
            if (d0 >= limit) d0 = limit - 1;
            rec[d0] = pack_rec(si, gx, gy, gz);
            unsigned d1 = atomicAdd(&cursor[ri >> BIN_SHIFT], 1u);
            if (d1 >= limit) d1 = limit - 1;
            rec[d1] = pack_rec(ri, -gx, -gy, -gz);
            float ex = rij[3 * e], ey = rij[3 * e + 1], ez = rij[3 * e + 2];
            int g = batch[ri];
            int* a = &s_acc[6 * g];
            atomicAdd(&a[0], __float2int_rn(ex * gx * VSCALE));
            atomicAdd(&a[1], __float2int_rn(ey * gy * VSCALE));
            atomicAdd(&a[2], __float2int_rn(ez * gz * VSCALE));
            atomicAdd(&a[3], __float2int_rn(ex * gy * VSCALE));
            atomicAdd(&a[4], __float2int_rn(ey * gz * VSCALE));
            atomicAdd(&a[5], __float2int_rn(ez * gx * VSCALE));
        }
    }

    __syncthreads();
    for (int t = threadIdx.x; t < SLOTS; t += TPB)
        apart[(size_t)t * NBLKS + blockIdx.x] = (float)s_acc[t] * VINV;
}

// ------------------------------------------------------------- B: accumulate
__global__ __launch_bounds__(TPB) void bin_accum_kernel(
    const uint2* __restrict__ rec, const unsigned* __restrict__ cursor,
    float* __restrict__ bpart, unsigned cap) {
    __shared__ int lf[SUBSZ * 3];                      // 24KB, fixed-point 2^20
    const int sl = blockIdx.x % SSL;
    const int r2 = blockIdx.x / SSL;
    const int st = r2 & (NSUB - 1);
    const int bin = r2 >> 1;                           // NSUB == 2

    int4* lf4 = (int4*)lf;
    for (int t = threadIdx.x; t < SUBSZ * 3 / 4; t += TPB)
        lf4[t] = make_int4(0, 0, 0, 0);
    __syncthreads();

    const unsigned base = (unsigned)bin * cap;
    unsigned cntb = cursor[bin] - base;
    if (cntb > cap) cntb = cap;                        // guard
    const unsigned chunk = (cntb + SSL - 1) / SSL;
    unsigned r0 = (unsigned)sl * chunk;
    unsigned r1 = r0 + chunk;
    if (r0 > cntb) r0 = cntb;
    if (r1 > cntb) r1 = cntb;
#pragma unroll 4
    for (unsigned r = r0 + threadIdx.x; r < r1; r += TPB) {
        uint2 w = rec[(size_t)base + r];
        unsigned lid = w.y >> 16;
        if ((int)(lid >> SUB_SHIFT) == st) {
            unsigned l2 = lid & (SUBSZ - 1);
            float fx = __half2float(__ushort_as_half((unsigned short)(w.x & 0xffffu)));
            float fy = __half2float(__ushort_as_half((unsigned short)(w.x >> 16)));
            float fz = __half2float(__ushort_as_half((unsigned short)(w.y & 0xffffu)));
            atomicAdd(&lf[l2 * 3 + 0], __float2int_rn(fx * FSCALE));
            atomicAdd(&lf[l2 * 3 + 1], __float2int_rn(fy * FSCALE));
            atomicAdd(&lf[l2 * 3 + 2], __float2int_rn(fz * FSCALE));
        }
    }
    __syncthreads();
    float4* dst = (float4*)(bpart + (size_t)blockIdx.x * (SUBSZ * 3));
    for (int t = threadIdx.x; t < SUBSZ * 3 / 4; t += TPB) {
        int4 v = lf4[t];
        dst[t] = make_float4((float)v.x * FINV, (float)v.y * FINV,
                             (float)v.z * FINV, (float)v.w * FINV);
    }
}

// ------------------------------------------------------------- C: force out
__global__ __launch_bounds__(TPB) void force_kernel(
    const float* __restrict__ bpart, const float* __restrict__ pos_grad,
    float* __restrict__ force, long n3) {
    long j = (long)blockIdx.x * TPB + threadIdx.x;
    const long gs = (long)gridDim.x * TPB;
    for (; j < n3; j += gs) {
        unsigned i = (unsigned)(j / 3);
        unsigned c = (unsigned)(j - 3L * i);
        unsigned bin = i >> BIN_SHIFT;
        unsigned st = (i >> SUB_SHIFT) & (NSUB - 1);
        unsigned l2 = i & (SUBSZ - 1);
        float acc = -pos_grad[j];
        size_t tb = ((size_t)(bin * NSUB + st) * SSL) * (SUBSZ * 3) + l2 * 3 + c;
#pragma unroll
        for (int sl = 0; sl < SSL; ++sl)
            acc += bpart[tb + (size_t)sl * (SUBSZ * 3)];
        force[j] = acc;
    }
}

// ------------------------------------------------------------- R: stress out
__global__ __launch_bounds__(TPB) void stress_kernel(
    const float* __restrict__ apart,
    const float* __restrict__ cell_grad, const float* __restrict__ les_cell,
    const float* __restrict__ vol, float* __restrict__ stress, int slots) {
    int t = blockIdx.x;
    if (t >= slots) return;
    __shared__ float red[TPB];
    float s = 0.f;
    const float* row = apart + (size_t)t * NBLKS;
    for (int j = threadIdx.x; j < NBLKS; j += TPB) s += row[j];
    red[threadIdx.x] = s;
    __syncthreads();
    for (int w = TPB / 2; w > 0; w >>= 1) {
        if (threadIdx.x < w) red[threadIdx.x] += red[threadIdx.x + w];
        __syncthreads();
    }
    if (threadIdx.x == 0) {
        int g = t / 6, c = t - 6 * g;
        const int va[6] = {0, 1, 2, 0, 1, 0};
        const int vb[6] = {0, 1, 2, 1, 2, 2};
        int a = va[c], bb = vb[c];
        const float* L = les_cell + 9 * g;
        const float* Gm = cell_grad + 9 * g;
        float lr = L[a] * Gm[bb] + L[3 + a] * Gm[3 + bb] + L[6 + a] * Gm[6 + bb];
        stress[t] = (-red[0] - lr) / vol[g];
    }
}

// ---------------------------------------------------- fallback (round-1 path)
__global__ void init_force_kernel(const float4* __restrict__ pg4,
                                  float4* __restrict__ f4, int n4,
                                  const float* __restrict__ pg,
                                  float* __restrict__ f, int n) {
    int i = blockIdx.x * blockDim.x + threadIdx.x;
    int s = gridDim.x * blockDim.x;
    for (int k = i; k < n4; k += s) {
        float4 v = pg4[k];
        f4[k] = make_float4(-v.x, -v.y, -v.z, -v.w);
    }
    for (int k = n4 * 4 + i; k < n; k += s) f[k] = -pg[k];
}

__global__ __launch_bounds__(256) void edge_dev_kernel(
    const float* __restrict__ rij, const float* __restrict__ fij,
    const int* __restrict__ idx0, const int* __restrict__ idx1,
    const int* __restrict__ batch,
    float* __restrict__ force, float* __restrict__ partials, int E) {
    __shared__ float s_acc[SLOTS];
    for (int t = threadIdx.x; t < SLOTS; t += blockDim.x) s_acc[t] = 0.0f;
    __syncthreads();
    const int stride = gridDim.x * blockDim.x;
    const int tid0 = blockIdx.x * blockDim.x + threadIdx.x;
    for (int e = tid0; e < E; e += stride) {
        float ex = rij[3 * e], ey = rij[3 * e + 1], ez = rij[3 * e + 2];
        float gx = fij[3 * e], gy = fij[3 * e + 1], gz = fij[3 * e + 2];
        int si = idx0[e], ri = idx1[e];
        atomicAdd(&force[3 * si + 0], gx);
        atomicAdd(&force[3 * si + 1], gy);
        atomicAdd(&force[3 * si + 2], gz);
        atomicAdd(&force[3 * ri + 0], -gx);
        atomicAdd(&force[3 * ri + 1], -gy);
        atomicAdd(&force[3 * ri + 2], -gz);
        int g = batch[ri];
        float* a = &s_acc[6 * g];
        atomicAdd(&a[0], ex * gx);
        atomicAdd(&a[1], ey * gy);
        atomicAdd(&a[2], ez * gz);
        atomicAdd(&a[3], ex * gy);
        atomicAdd(&a[4], ey * gz);
        atomicAdd(&a[5], ez * gx);
    }
    __syncthreads();
    for (int t = threadIdx.x; t < SLOTS; t += blockDim.x)
        partials[(size_t)blockIdx.x * SLOTS + t] = s_acc[t];
}

__global__ void reduce_finalize_kernel(const float* __restrict__ partials, int nblocks,
                                       const float* __restrict__ cell_grad,
                                       const float* __restrict__ les_cell,
                                       const float* __restrict__ vol,
                                       float* __restrict__ stress_out, int slots) {
    int t = blockIdx.x * blockDim.x + threadIdx.x;
    if (t >= slots) return;
    float s = 0.0f;
    for (int b = 0; b < nblocks; ++b) s += partials[(size_t)b * SLOTS + t];
    int g = t / 6, c = t - 6 * g;
    const int va[6] = {0, 1, 2, 0, 1, 0};
    const int vb[6] = {0, 1, 2, 1, 2, 2};
    int a = va[c], bb = vb[c];
    const float* L = les_cell + 9 * g;
    const float* G = cell_grad + 9 * g;
    float lr = L[a] * G[bb] + L[3 + a] * G[3 + bb] + L[6 + a] * G[6 + bb];
    stress_out[t] = (-s - lr) / vol[g];
}

// ------------------------------------------------------------------ launcher
static inline size_t alignup(size_t x) { return (x + 255) & ~(size_t)255; }

extern "C" void kernel_launch(void* const* d_in, const int* in_sizes, int n_in,
                              void* d_out, int out_size, void* d_ws, size_t ws_size,
                              hipStream_t stream) {
    const float* rij = (const float*)d_in[0];
    const float* fij = (const float*)d_in[1];
    const float* pos_grad = (const float*)d_in[2];
    const float* cell_grad = (const float*)d_in[3];
    const float* les_cell = (const float*)d_in[4];
    const float* vol = (const float*)d_in[5];
    const int* edge_idx = (const int*)d_in[6];
    const int* batch = (const int*)d_in[7];

    const int E = in_sizes[0] / 3;
    const int N = in_sizes[2] / 3;
    const int ngr = in_sizes[5];
    const int slots = 6 * ngr;

    float* force = (float*)d_out;
    float* stress = (float*)d_out + (size_t)N * 3;

    const int nbins = (N + BINSZ - 1) >> BIN_SHIFT;
    const long N3 = (long)N * 3;

    // per-bin record capacity: mean * 1.03 + pad (≈15 sigma for Poisson bins)
    double meanrec = 2.0 * (double)E * (double)BINSZ / (double)(N > 0 ? N : 1);
    size_t cap_sz = (size_t)(meanrec * 1.03) + 2048;
    if (cap_sz > (size_t)2 * E + 2048) cap_sz = (size_t)2 * E + 2048;
    const unsigned cap = (unsigned)cap_sz;
    const size_t rec_elems = ((size_t)nbins + 1) * cap;   // +1 cap guard stride
    const unsigned limit = (unsigned)rec_elems;

    // workspace layout
    size_t off = 0;
    const size_t o_rec = off;   off += alignup(rec_elems * 8);
    const size_t o_cur = off;   off += alignup(MAXB * 4);
    const size_t o_apart = off; off += alignup((size_t)SLOTS * NBLKS * 4);
    const size_t o_bpart = off; off += alignup((size_t)nbins * NSUB * SSL * (SUBSZ * 3) * 4);
    const bool fit = (off <= ws_size) && (nbins <= MAXB) && (ngr <= MAXG) && (E >= 4) &&
                     (rec_elems < 0xFFFFFFFFull);

    if (fit) {
        char* ws = (char*)d_ws;
        uint2* rec = (uint2*)(ws + o_rec);
        unsigned* cursor = (unsigned*)(ws + o_cur);
        float* apart = (float*)(ws + o_apart);
        float* bpart = (float*)(ws + o_bpart);

        init_cursor_kernel<<<1, 64, 0, stream>>>(cursor, nbins, cap);

        const size_t smem = (size_t)nbins * CAP * 8 + (size_t)nbins * 8 + SLOTS * 4;
        scatter_kernel<<<NBLKS, TPB, smem, stream>>>(
            rij, fij, edge_idx, edge_idx + E, batch, cursor, rec, apart,
            E, nbins, limit);

        bin_accum_kernel<<<nbins * NSUB * SSL, TPB, 0, stream>>>(
            rec, cursor, bpart, cap);

        int fblocks = (int)((N3 + TPB - 1) / TPB);
        if (fblocks > 4096) fblocks = 4096;
        force_kernel<<<fblocks, TPB, 0, stream>>>(bpart, pos_grad, force, N3);

        stress_kernel<<<slots, TPB, 0, stream>>>(apart, cell_grad, les_cell, vol,
                                                 stress, slots);
    } else {
        // device-atomic fallback (proven correct, slow)
        float* partials = (float*)d_ws;
        int eblocks = 512;
        size_t need = (size_t)eblocks * SLOTS * sizeof(float);
        if (need > ws_size) {
            int fit2 = (int)(ws_size / (SLOTS * sizeof(float)));
            eblocks = fit2 > 0 ? fit2 : 1;
        }
        int n = (int)N3, n4 = n / 4;
        int blocks = (n4 + 255) / 256;
        if (blocks > 1024) blocks = 1024;
        if (blocks < 1) blocks = 1;
        init_force_kernel<<<blocks, 256, 0, stream>>>(
            (const float4*)pos_grad, (float4*)force, n4, pos_grad, force, n);
        edge_dev_kernel<<<eblocks, 256, 0, stream>>>(rij, fij, edge_idx, edge_idx + E,
                                                     batch, force, partials, E);
        reduce_finalize_kernel<<<6, 64, 0, stream>>>(partials, eblocks, cell_grad,
                                                     les_cell, vol, stress, slots);
    }
}